// Round 2
// baseline (775.868 us; speedup 1.0000x reference)
//
#include <hip/hip_runtime.h>

#define N_NODES 500000
#define N_EDGES 8000000
#define N_GRAPHS 4096

// ---------------- binned-aggregation v5 ----------------
// v4 -> v5: p1 tile 4096 -> 2048 edges (LDS 22KB -> 4 blocks/CU = 100% occ
// potential) and, critically, deep MLP: src prefetched in phase 1 with dst,
// and ALL phase-3 gathers (xd, xs, ea) batch-issued into registers before
// any compute, so each wave keeps ~12 loads in flight instead of ~3
// (R1 showed VGPR=32: compiler had serialized the loads; occupancy alone
// bought only 15%). p2 stores AoS float2 pairs so pool reads 8B/node/slice.
#define NB 128
#define BIN_SHIFT 12
#define BIN_NODES 4096
#define NBINS 123                   // ceil(500000/4096)
#define BIN_CAP 66560               // mean 65041, sigma ~254 -> +6sigma; ovf-safe
#define T_EDGES 2048
#define P1_THREADS 512
#define EPT (T_EDGES / P1_THREADS)  // 4
#define P1_GRID ((N_EDGES + T_EDGES - 1) / T_EDGES)   // 3907
#define K 4                         // sub-blocks per bin in p2
#define P2_GRID (NBINS * K)         // 492
#define SLICE_F (BIN_NODES * 2)     // 8192 floats = 32KB per slice
#define FXS 131072.0f               // 2^17; fields 25b, m < 250
#define FXI (1.0f / 131072.0f)
#define M_MAX 250.0f
#define OVF_CAP 8192
#define SGRID ((N_NODES + 255) / 256)

// ---------------- ws layout (byte offsets) ----------------
#define OFF_CURS_A   0          // 128 u32
#define OFF_CURS_B   512
#define OFF_OVFC_A   1024
#define OFF_OVFC_B   1280
#define ZERO_SMALL   1536       // memset range per call
#define OFF_STARTS_A 4096       // 4097 u32, padded
#define OFF_STARTS_B 20736
#define OFF_MEAN_A   37376      // 4096*3 f32
#define OFF_MEAN_B   86528
#define OFF_OVF_A    135680     // 8192 float4
#define OFF_OVF_B    266752
#define OFF_SCRATCH  397824     // NBINS*K*SLICE_F f32 = 16,121,856 B (shared A/B)
#define OFF_BINS     16519680   // NBINS*BIN_CAP u64 = 65,495,040 B (shared A/B)
#define WS_NEED      82014720ull

__device__ __forceinline__ float2 ntload_f2(const float2* p) {
    unsigned long long v = __builtin_nontemporal_load((const unsigned long long*)p);
    float2 r;
    r.x = __uint_as_float((unsigned int)v);
    r.y = __uint_as_float((unsigned int)(v >> 32));
    return r;
}

// ===========================================================================
// Pass 1: LDS counting sort by dst bin, coalesced flush to reserved ranges.
// dst+src kept in VGPRs from phase 1; phase 3 batch-issues all gathers.
// ===========================================================================
__global__ __launch_bounds__(512, 8) void p1_kernel(
    const float* __restrict__ x, const int* __restrict__ ei,
    const float* __restrict__ ea,
    const float* __restrict__ Wf, const float* __restrict__ bfv,
    const float* __restrict__ Ws, const float* __restrict__ bsv,
    unsigned long long* __restrict__ bins, unsigned int* __restrict__ cursors,
    unsigned int* __restrict__ ovf_cnt, float4* __restrict__ ovf)
{
    __shared__ unsigned long long sorted[T_EDGES];   // 16 KB
    __shared__ unsigned int whist[8][NB];            // 4 KB; reused as binof[] later
    __shared__ unsigned int base[NB];
    __shared__ unsigned int cur[NB];
    __shared__ unsigned int gbase[NB];
    __shared__ unsigned int ntot_s;
    unsigned char* binof = (unsigned char*)whist;    // alias: whist dead after phase 2

    int t = threadIdx.x;
    int wave = t >> 6;
    int ebase = blockIdx.x * T_EDGES;

    for (int i = t; i < 8 * NB; i += P1_THREADS) ((unsigned int*)whist)[i] = 0;
    __syncthreads();

    // phase 1: histogram; keep dst AND src in registers for phase 3
    int d[EPT], s[EPT];
#pragma unroll
    for (int i = 0; i < EPT; ++i) {
        int e = ebase + i * P1_THREADS + t;
        if (e < N_EDGES) {
            d[i] = __builtin_nontemporal_load(ei + N_EDGES + e);
            s[i] = __builtin_nontemporal_load(ei + e);
        } else { d[i] = -1; s[i] = 0; }
        if (d[i] >= 0)
            atomicAdd(&whist[wave][((unsigned)d[i]) >> BIN_SHIFT], 1u);
    }
    __syncthreads();

    // phase 2: per-bin totals, exclusive scan (wave 0, 2 bins/lane), reserve.
    // Returning global atomics ISSUED here; gbase written after phase 3 so
    // their latency hides under the compute loop.
    unsigned g0 = 0, g1 = 0;
    if (t < 64) {
        unsigned tot0 = 0, tot1 = 0;
#pragma unroll
        for (int w = 0; w < 8; ++w) { tot0 += whist[w][2*t]; tot1 += whist[w][2*t+1]; }
        unsigned pair = tot0 + tot1;
        unsigned v = pair;
#pragma unroll
        for (int off = 1; off < 64; off <<= 1) {
            unsigned u = __shfl_up(v, off);
            if (t >= off) v += u;
        }
        unsigned excl = v - pair;
        base[2*t]   = excl;        cur[2*t]   = excl;
        base[2*t+1] = excl + tot0; cur[2*t+1] = excl + tot0;
        if (t == 63) ntot_s = v;
        g0 = tot0 ? atomicAdd(&cursors[2*t],   tot0) : 0u;
        g1 = tot1 ? atomicAdd(&cursors[2*t+1], tot1) : 0u;
    }
    __syncthreads();

    // phase 3a: batch-issue ALL gathers (deep MLP; ~12 loads in flight)
    float2 xdv[EPT], xsv[EPT], eav[EPT];
#pragma unroll
    for (int i = 0; i < EPT; ++i) {
        int e = ebase + i * P1_THREADS + t;
        if (e < N_EDGES) {
            xdv[i] = ((const float2*)x)[d[i]];
            xsv[i] = ((const float2*)x)[s[i]];
            eav[i] = ntload_f2((const float2*)ea + e);
        }
    }

    // phase 3b: compute m, place into sorted LDS slots (+ bin byte per slot)
    float wf[12], wsv[12];
#pragma unroll
    for (int i = 0; i < 12; ++i) { wf[i] = Wf[i]; wsv[i] = Ws[i]; }
    float bf0 = bfv[0], bf1 = bfv[1], bs0 = bsv[0], bs1 = bsv[1];

#pragma unroll
    for (int i = 0; i < EPT; ++i) {
        int e = ebase + i * P1_THREADS + t;
        if (e >= N_EDGES) continue;
        int dst = d[i];
        float z0 = xdv[i].x, z1 = xdv[i].y;
        float z2 = xsv[i].x, z3 = xsv[i].y;
        float z4 = eav[i].x, z5 = eav[i].y;

        float f0 = bf0 + z0*wf[0] + z1*wf[2] + z2*wf[4] + z3*wf[6] + z4*wf[8]  + z5*wf[10];
        float f1 = bf1 + z0*wf[1] + z1*wf[3] + z2*wf[5] + z3*wf[7] + z4*wf[9]  + z5*wf[11];
        float s0 = bs0 + z0*wsv[0] + z1*wsv[2] + z2*wsv[4] + z3*wsv[6] + z4*wsv[8]  + z5*wsv[10];
        float s1 = bs1 + z0*wsv[1] + z1*wsv[3] + z2*wsv[5] + z3*wsv[7] + z4*wsv[9]  + z5*wsv[11];

        float m0 = (1.f/(1.f+__expf(-f0))) * (fmaxf(s0,0.f) + __logf(1.f+__expf(-fabsf(s0))));
        float m1 = (1.f/(1.f+__expf(-f1))) * (fmaxf(s1,0.f) + __logf(1.f+__expf(-fabsf(s1))));

        int b = (int)((unsigned)dst >> BIN_SHIFT);
        unsigned slot = atomicAdd(&cur[b], 1u);
        unsigned long long pk = 0ull;     // neutral: adds 0.0 to node b<<12
        if (m0 < M_MAX && m1 < M_MAX) {
            unsigned fx0 = __float2uint_rn(m0 * FXS);
            unsigned fx1 = __float2uint_rn(m1 * FXS);
            pk = (unsigned long long)((unsigned)dst & (BIN_NODES - 1))
               | ((unsigned long long)fx0 << 12)
               | ((unsigned long long)fx1 << 37);
        } else {
            unsigned oi = atomicAdd(ovf_cnt, 1u);
            if (oi < OVF_CAP) ovf[oi] = make_float4(__int_as_float(dst), m0, m1, 0.f);
        }
        sorted[slot] = pk;
        binof[slot] = (unsigned char)b;
    }
    if (t < 64) { gbase[2*t] = g0; gbase[2*t+1] = g1; }   // waits on atomics here
    __syncthreads();

    // phase 4: coalesced flush (runs of ~16 edges = 128B contiguous)
    int ntot = (int)ntot_s;
    for (int p = t; p < ntot; p += P1_THREADS) {
        int lo = (int)binof[p];
        unsigned gpos = gbase[lo] + (unsigned)(p - (int)base[lo]);
        unsigned long long v = sorted[p];
        if (gpos < BIN_CAP) {
            __builtin_nontemporal_store(v, &bins[(size_t)lo * BIN_CAP + gpos]);
        } else {                          // cap overflow (p~1e-9): exact replay
            int local = (int)(v & (BIN_NODES - 1));
            float m0 = (float)((unsigned)((v >> 12) & 0x1FFFFFFu)) * FXI;
            float m1 = (float)((unsigned)((v >> 37) & 0x1FFFFFFu)) * FXI;
            int dst = (lo << BIN_SHIFT) + local;
            unsigned oi = atomicAdd(ovf_cnt, 1u);
            if (oi < OVF_CAP) ovf[oi] = make_float4(__int_as_float(dst), m0, m1, 0.f);
        }
    }
}

// ===========================================================================
// Pass 2: K=4 sub-blocks per bin; 32KB private SoA LDS slice (full 32-bank
// spread for the atomics); epilogue converts to AoS float2 pairs so pool
// reads 8B per node per slice.
// ===========================================================================
__global__ __launch_bounds__(512, 8) void p2_kernel(
    const unsigned long long* __restrict__ bins,
    const unsigned int* __restrict__ cursors,
    float* __restrict__ scratch)
{
    __shared__ float acc[SLICE_F];        // 32 KB: [0..4095]=m0, [4096..8191]=m1
    int b = blockIdx.x >> 2;
    int k = blockIdx.x & 3;
    int t = threadIdx.x;
#pragma unroll
    for (int i = t; i < SLICE_F; i += 512) acc[i] = 0.f;
    __syncthreads();

    int n = (int)min(cursors[b], (unsigned)BIN_CAP);
    int s = (n * k) / K, e = (n * (k + 1)) / K;
    const unsigned long long* bp = bins + (size_t)b * BIN_CAP;
    for (int i = s + t; i < e; i += 512) {
        unsigned long long v = __builtin_nontemporal_load(bp + i);
        int local = (int)(v & (BIN_NODES - 1));
        float m0 = (float)((unsigned)((v >> 12) & 0x1FFFFFFu)) * FXI;
        float m1 = (float)((unsigned)((v >> 37) & 0x1FFFFFFu)) * FXI;
        atomicAdd(&acc[local],             m0);
        atomicAdd(&acc[BIN_NODES + local], m1);
    }
    __syncthreads();

    // AoS epilogue: float4 = {m0[2i], m1[2i], m0[2i+1], m1[2i+1]}
    float4* dst = (float4*)(scratch + (size_t)(b * K + k) * SLICE_F);
#pragma unroll
    for (int i = t; i < BIN_NODES / 2; i += 512) {
        float a0 = acc[2*i],             a1 = acc[2*i + 1];
        float b0 = acc[BIN_NODES + 2*i], b1 = acc[BIN_NODES + 2*i + 1];
        dst[i] = make_float4(a0, b0, a1, b1);
    }
}

// Replay overflow edges into slice k=0 (statistically never taken).
__global__ __launch_bounds__(256) void ovf_kernel(
    const float4* __restrict__ ovf, const unsigned int* __restrict__ ovf_cnt,
    float* __restrict__ scratch)
{
    int n = (int)min(*ovf_cnt, (unsigned)OVF_CAP);
    for (int i = threadIdx.x; i < n; i += 256) {
        float4 r = ovf[i];
        int dst = __float_as_int(r.x);
        int b = dst >> BIN_SHIFT, local = dst & (BIN_NODES - 1);
        float* p = scratch + (size_t)(b * K) * SLICE_F + 2 * local;
        unsafeAtomicAdd(p,     r.y);
        unsafeAtomicAdd(p + 1, r.z);
    }
}

// Segment boundaries of sorted batch -> starts[0..N_GRAPHS]. Both branches
// in one dispatch (blockIdx >= SGRID handles branch B).
__global__ __launch_bounds__(256) void starts_kernel(
    const int* __restrict__ ba, const int* __restrict__ bb,
    unsigned int* __restrict__ sa, unsigned int* __restrict__ sb)
{
    int blk = blockIdx.x;
    const int* batch = ba;
    unsigned int* starts = sa;
    if (blk >= SGRID) { blk -= SGRID; batch = bb; starts = sb; }
    int i = blk * 256 + threadIdx.x;
    if (i >= N_NODES) return;
    int b1 = batch[i];
    if (i == 0) {
        for (int g = 0; g <= b1; ++g) starts[g] = 0;
    } else {
        int b0 = batch[i - 1];
        for (int g = b0 + 1; g <= b1; ++g) starts[g] = i;
    }
    if (i == N_NODES - 1) {
        for (int g = b1 + 1; g <= N_GRAPHS; ++g) starts[g] = N_NODES;
    }
}

// Pool: 4 graphs per block (one wave each); agg = sum of K slices (AoS
// float2), consecutive nodes -> coalesced 8B loads in each slice.
__global__ __launch_bounds__(256) void pool2_kernel(
    const float* __restrict__ x, const float* __restrict__ scratch,
    const unsigned int* __restrict__ starts,
    const float* __restrict__ W1, const float* __restrict__ b1,
    float* __restrict__ mean_out)
{
    int wave = threadIdx.x >> 6, lane = threadIdx.x & 63;
    int g = blockIdx.x * 4 + wave;

    float w00 = W1[0], w01 = W1[1], w02 = W1[2];
    float w10 = W1[3], w11 = W1[4], w12 = W1[5];
    float c0 = b1[0], c1 = b1[1], c2 = b1[2];

    const float2* sc2 = (const float2*)scratch;
    int s = (int)starts[g], e = (int)starts[g + 1];
    float a0 = 0.f, a1 = 0.f, a2 = 0.f;
    for (int i = s + lane; i < e; i += 64) {
        int b = i >> BIN_SHIFT, local = i & (BIN_NODES - 1);
        size_t f2base = (size_t)(b * K) * BIN_NODES + local;   // slice = 4096 f2
        float2 g0 = sc2[f2base];
        float2 g1 = sc2[f2base + BIN_NODES];
        float2 g2 = sc2[f2base + 2 * BIN_NODES];
        float2 g3 = sc2[f2base + 3 * BIN_NODES];
        float2 xv = ((const float2*)x)[i];
        float h0 = xv.x + g0.x + g1.x + g2.x + g3.x;
        float h1 = xv.y + g0.y + g1.y + g2.y + g3.y;
        a0 += fmaxf(h0*w00 + h1*w10 + c0, 0.f);
        a1 += fmaxf(h0*w01 + h1*w11 + c1, 0.f);
        a2 += fmaxf(h0*w02 + h1*w12 + c2, 0.f);
    }
#pragma unroll
    for (int off = 32; off; off >>= 1) {
        a0 += __shfl_down(a0, off);
        a1 += __shfl_down(a1, off);
        a2 += __shfl_down(a2, off);
    }
    if (lane == 0) {
        float inv = 1.0f / fmaxf((float)(e - s), 1.0f);
        mean_out[3*(size_t)g]     = a0 * inv;
        mean_out[3*(size_t)g + 1] = a1 * inv;
        mean_out[3*(size_t)g + 2] = a2 * inv;
    }
}

// Final MLP + MSE loss (single block).
__global__ __launch_bounds__(1024) void final_kernel(
    const float* __restrict__ ma, const float* __restrict__ mb,
    const float* __restrict__ W2, const float* __restrict__ b2,
    const float* __restrict__ targets,
    float* __restrict__ out)
{
    __shared__ float red[1024];
    float w0 = W2[0], w1 = W2[1], w2 = W2[2], w3 = W2[3], w4 = W2[4], w5 = W2[5];
    float bias = b2[0];

    float lsum = 0.f;
    for (int g = threadIdx.x; g < N_GRAPHS; g += 1024) {
        float v = bias
                + ma[3*(size_t)g]*w0 + ma[3*(size_t)g+1]*w1 + ma[3*(size_t)g+2]*w2
                + mb[3*(size_t)g]*w3 + mb[3*(size_t)g+1]*w4 + mb[3*(size_t)g+2]*w5;
        v = fmaxf(v, 0.f);
        out[g] = v;
        float d = v - targets[g];
        lsum += d * d;
    }
    red[threadIdx.x] = lsum;
    __syncthreads();
#pragma unroll
    for (int off = 512; off; off >>= 1) {
        if (threadIdx.x < (unsigned)off) red[threadIdx.x] += red[threadIdx.x + off];
        __syncthreads();
    }
    if (threadIdx.x == 0) out[N_GRAPHS] = red[0] * (1.0f / (float)N_GRAPHS);
}

// ===========================================================================
// Fallback path (ws too small): R2's u64-packed global-atomic kernel.
// ===========================================================================
#define FB_SCALE 4194304.0f
#define FB_INV   2.384185791015625e-07f

__global__ __launch_bounds__(256) void fb_edge_kernel(
    const float* __restrict__ x, const int* __restrict__ ei,
    const float* __restrict__ ea,
    const float* __restrict__ Wf, const float* __restrict__ bfv,
    const float* __restrict__ Ws, const float* __restrict__ bsv,
    unsigned long long* __restrict__ agg)
{
    float wf[12], ws[12];
#pragma unroll
    for (int i = 0; i < 12; ++i) { wf[i] = Wf[i]; ws[i] = Ws[i]; }
    float bf0 = bfv[0], bf1 = bfv[1], bs0 = bsv[0], bs1 = bsv[1];

    int e = blockIdx.x * 256 + threadIdx.x;
    int src = ei[e];
    int dst = ei[N_EDGES + e];
    float2 xd = ((const float2*)x)[dst];
    float2 xs = ((const float2*)x)[src];
    float2 ev = ((const float2*)ea)[e];
    float z0 = xd.x, z1 = xd.y, z2 = xs.x, z3 = xs.y, z4 = ev.x, z5 = ev.y;

    float f0 = bf0 + z0*wf[0] + z1*wf[2] + z2*wf[4] + z3*wf[6] + z4*wf[8]  + z5*wf[10];
    float f1 = bf1 + z0*wf[1] + z1*wf[3] + z2*wf[5] + z3*wf[7] + z4*wf[9]  + z5*wf[11];
    float s0 = bs0 + z0*ws[0] + z1*ws[2] + z2*ws[4] + z3*ws[6] + z4*ws[8]  + z5*ws[10];
    float s1 = bs1 + z0*ws[1] + z1*ws[3] + z2*ws[5] + z3*ws[7] + z4*ws[9]  + z5*ws[11];

    float m0 = (1.f/(1.f+__expf(-f0))) * (fmaxf(s0,0.f) + __logf(1.f+__expf(-fabsf(s0))));
    float m1 = (1.f/(1.f+__expf(-f1))) * (fmaxf(s1,0.f) + __logf(1.f+__expf(-fabsf(s1))));

    unsigned int fx0 = __float2uint_rn(m0 * FB_SCALE);
    unsigned int fx1 = __float2uint_rn(m1 * FB_SCALE);
    atomicAdd(&agg[dst], (unsigned long long)fx0 | ((unsigned long long)fx1 << 32));
}

__global__ __launch_bounds__(64) void fb_pool_kernel(
    const float* __restrict__ x, const unsigned long long* __restrict__ agg,
    const int* __restrict__ batch,
    const float* __restrict__ W1, const float* __restrict__ b1,
    float* __restrict__ mean_out)
{
    int b = blockIdx.x;
    float w00 = W1[0], w01 = W1[1], w02 = W1[2];
    float w10 = W1[3], w11 = W1[4], w12 = W1[5];
    float c0 = b1[0], c1 = b1[1], c2 = b1[2];

    int lo = 0, hi = N_NODES;
    while (lo < hi) { int mid = (lo + hi) >> 1; if (batch[mid] < b) lo = mid + 1; else hi = mid; }
    int seg_s = lo;
    hi = N_NODES;
    while (lo < hi) { int mid = (lo + hi) >> 1; if (batch[mid] < b + 1) lo = mid + 1; else hi = mid; }
    int seg_e = lo;

    float a0 = 0.f, a1 = 0.f, a2 = 0.f;
    for (int i = seg_s + (int)threadIdx.x; i < seg_e; i += 64) {
        unsigned long long v = agg[i];
        float g0 = (float)(unsigned int)(v & 0xffffffffull) * FB_INV;
        float g1 = (float)(unsigned int)(v >> 32) * FB_INV;
        float2 xv = ((const float2*)x)[i];
        float h0 = xv.x + g0, h1 = xv.y + g1;
        a0 += fmaxf(h0*w00 + h1*w10 + c0, 0.f);
        a1 += fmaxf(h0*w01 + h1*w11 + c1, 0.f);
        a2 += fmaxf(h0*w02 + h1*w12 + c2, 0.f);
    }
#pragma unroll
    for (int off = 32; off; off >>= 1) {
        a0 += __shfl_down(a0, off);
        a1 += __shfl_down(a1, off);
        a2 += __shfl_down(a2, off);
    }
    if (threadIdx.x == 0) {
        float inv = 1.0f / fmaxf((float)(seg_e - seg_s), 1.0f);
        mean_out[3*(size_t)b]     = a0 * inv;
        mean_out[3*(size_t)b + 1] = a1 * inv;
        mean_out[3*(size_t)b + 2] = a2 * inv;
    }
}

extern "C" void kernel_launch(void* const* d_in, const int* in_sizes, int n_in,
                              void* d_out, int out_size, void* d_ws, size_t ws_size,
                              hipStream_t stream) {
    const float* x_a     = (const float*)d_in[0];
    const int*   ei_a    = (const int*)  d_in[1];
    const float* ea_a    = (const float*)d_in[2];
    const int*   batch_a = (const int*)  d_in[3];
    const float* x_b     = (const float*)d_in[4];
    const int*   ei_b    = (const int*)  d_in[5];
    const float* ea_b    = (const float*)d_in[6];
    const int*   batch_b = (const int*)  d_in[7];
    const float* targets = (const float*)d_in[8];
    const float* Wf = (const float*)d_in[10];
    const float* bf = (const float*)d_in[11];
    const float* Ws = (const float*)d_in[12];
    const float* bs = (const float*)d_in[13];
    const float* W1 = (const float*)d_in[14];
    const float* b1 = (const float*)d_in[15];
    const float* W2 = (const float*)d_in[16];
    const float* b2 = (const float*)d_in[17];
    float* out = (float*)d_out;
    char* ws = (char*)d_ws;

    if (ws_size >= WS_NEED) {
        unsigned int* curs_a   = (unsigned int*)(ws + OFF_CURS_A);
        unsigned int* curs_b   = (unsigned int*)(ws + OFF_CURS_B);
        unsigned int* ovfc_a   = (unsigned int*)(ws + OFF_OVFC_A);
        unsigned int* ovfc_b   = (unsigned int*)(ws + OFF_OVFC_B);
        unsigned int* starts_a = (unsigned int*)(ws + OFF_STARTS_A);
        unsigned int* starts_b = (unsigned int*)(ws + OFF_STARTS_B);
        float* mean_a = (float*)(ws + OFF_MEAN_A);
        float* mean_b = (float*)(ws + OFF_MEAN_B);
        float4* ovf_a = (float4*)(ws + OFF_OVF_A);
        float4* ovf_b = (float4*)(ws + OFF_OVF_B);
        float* scratch = (float*)(ws + OFF_SCRATCH);            // shared A/B
        unsigned long long* bins = (unsigned long long*)(ws + OFF_BINS);

        hipMemsetAsync(ws, 0, ZERO_SMALL, stream);

        starts_kernel<<<2 * SGRID, 256, 0, stream>>>(batch_a, batch_b, starts_a, starts_b);

        // branch A (pool_a must precede p2_b: scratch is reused)
        p1_kernel<<<P1_GRID, P1_THREADS, 0, stream>>>(x_a, ei_a, ea_a, Wf, bf, Ws, bs,
                                                      bins, curs_a, ovfc_a, ovf_a);
        p2_kernel<<<P2_GRID, 512, 0, stream>>>(bins, curs_a, scratch);
        ovf_kernel<<<1, 256, 0, stream>>>(ovf_a, ovfc_a, scratch);
        pool2_kernel<<<N_GRAPHS / 4, 256, 0, stream>>>(x_a, scratch, starts_a, W1, b1, mean_a);

        // branch B
        p1_kernel<<<P1_GRID, P1_THREADS, 0, stream>>>(x_b, ei_b, ea_b, Wf, bf, Ws, bs,
                                                      bins, curs_b, ovfc_b, ovf_b);
        p2_kernel<<<P2_GRID, 512, 0, stream>>>(bins, curs_b, scratch);
        ovf_kernel<<<1, 256, 0, stream>>>(ovf_b, ovfc_b, scratch);
        pool2_kernel<<<N_GRAPHS / 4, 256, 0, stream>>>(x_b, scratch, starts_b, W1, b1, mean_b);

        final_kernel<<<1, 1024, 0, stream>>>(mean_a, mean_b, W2, b2, targets, out);
    } else {
        // Fallback: R2 path (u64 packed global atomics), needs ~8.1 MB ws.
        unsigned long long* aggu_a = (unsigned long long*)ws;
        unsigned long long* aggu_b = aggu_a + (size_t)N_NODES;
        float* mean_a = (float*)(aggu_b + (size_t)N_NODES);
        float* mean_b = mean_a + 3 * (size_t)N_GRAPHS;

        hipMemsetAsync(ws, 0, 2 * (size_t)N_NODES * sizeof(unsigned long long), stream);
        fb_edge_kernel<<<N_EDGES / 256, 256, 0, stream>>>(x_a, ei_a, ea_a, Wf, bf, Ws, bs, aggu_a);
        fb_edge_kernel<<<N_EDGES / 256, 256, 0, stream>>>(x_b, ei_b, ea_b, Wf, bf, Ws, bs, aggu_b);
        fb_pool_kernel<<<N_GRAPHS, 64, 0, stream>>>(x_a, aggu_a, batch_a, W1, b1, mean_a);
        fb_pool_kernel<<<N_GRAPHS, 64, 0, stream>>>(x_b, aggu_b, batch_b, W1, b1, mean_b);
        final_kernel<<<1, 1024, 0, stream>>>(mean_a, mean_b, W2, b2, targets, out);
    }
}

// Round 3
// 738.345 us; speedup vs baseline: 1.0508x; 1.0508x over previous
//
#include <hip/hip_runtime.h>

#define N_NODES 500000
#define N_EDGES 8000000
#define N_GRAPHS 4096

// ---------------- binned-aggregation v6 ----------------
// v5 -> v6: revert to T_EDGES=4096 (R1 anchor; v5's 2048 tile doubled
// per-block overhead and regressed). True deep-MLP in p1 phase 3:
//  - weights forced to SGPR via readfirstlane (frees ~24 VGPR),
//  - gathers double-buffered in chunks of 4 edges (12 loads in flight),
//  - chunk A issued BEFORE the phase-2 scan so it also hides the scan and
//    the returning cursor atomics,
//  - interior __syncthreads replaced by light barriers (lgkmcnt(0) +
//    raw s_barrier): hipcc's full vmcnt(0) drain at __syncthreads would
//    kill any pre-barrier load (R2 lesson: compiler also sinks batched
//    loads without sched_barrier(0) pins -> VGPR=28 and no ILP).
#define NB 128
#define BIN_SHIFT 12
#define BIN_NODES 4096
#define NBINS 123                   // ceil(500000/4096)
#define BIN_CAP 66560               // mean 65041, sigma ~254 -> +6sigma; ovf-safe
#define T_EDGES 4096
#define P1_THREADS 512
#define EPT (T_EDGES / P1_THREADS)  // 8
#define P1_GRID ((N_EDGES + T_EDGES - 1) / T_EDGES)   // 1954
#define K 4                         // sub-blocks per bin in p2
#define P2_GRID (NBINS * K)         // 492
#define SLICE_F (BIN_NODES * 2)     // 8192 floats = 32KB per slice
#define FXS 131072.0f               // 2^17; fields 25b, m < 250
#define FXI (1.0f / 131072.0f)
#define M_MAX 250.0f
#define OVF_CAP 8192
#define SGRID ((N_NODES + 255) / 256)

// ---------------- ws layout (byte offsets) ----------------
#define OFF_CURS_A   0          // 128 u32
#define OFF_CURS_B   512
#define OFF_OVFC_A   1024
#define OFF_OVFC_B   1280
#define ZERO_SMALL   1536       // memset range per call
#define OFF_STARTS_A 4096       // 4097 u32, padded
#define OFF_STARTS_B 20736
#define OFF_MEAN_A   37376      // 4096*3 f32
#define OFF_MEAN_B   86528
#define OFF_OVF_A    135680     // 8192 float4
#define OFF_OVF_B    266752
#define OFF_SCRATCH  397824     // NBINS*K*SLICE_F f32 = 16,121,856 B (shared A/B)
#define OFF_BINS     16519680   // NBINS*BIN_CAP u64 = 65,495,040 B (shared A/B)
#define WS_NEED      82014720ull

__device__ __forceinline__ float2 ntload_f2(const float2* p) {
    unsigned long long v = __builtin_nontemporal_load((const unsigned long long*)p);
    float2 r;
    r.x = __uint_as_float((unsigned int)v);
    r.y = __uint_as_float((unsigned int)(v >> 32));
    return r;
}

__device__ __forceinline__ float uniform_f(const float* p) {
    // uniform load -> SGPR (readfirstlane), frees a VGPR
    return __uint_as_float(__builtin_amdgcn_readfirstlane(__float_as_uint(*p)));
}

// LDS-only barrier: drain own LDS ops, raw s_barrier, no vmcnt(0) drain.
// sched_barrier(0) pins compiler/MIsched motion across it (guide rule #18).
#define LIGHT_BARRIER() do {                                   \
    __builtin_amdgcn_sched_barrier(0);                         \
    asm volatile("s_waitcnt lgkmcnt(0)" ::: "memory");         \
    __builtin_amdgcn_s_barrier();                              \
    __builtin_amdgcn_sched_barrier(0);                         \
} while (0)

// ===========================================================================
// Pass 1: LDS counting sort by dst bin, coalesced flush to reserved ranges.
// ===========================================================================
__global__ __launch_bounds__(512, 8) void p1_kernel(
    const float* __restrict__ x, const int* __restrict__ ei,
    const float* __restrict__ ea,
    const float* __restrict__ Wf, const float* __restrict__ bfv,
    const float* __restrict__ Ws, const float* __restrict__ bsv,
    unsigned long long* __restrict__ bins, unsigned int* __restrict__ cursors,
    unsigned int* __restrict__ ovf_cnt, float4* __restrict__ ovf)
{
    __shared__ unsigned long long sorted[T_EDGES];   // 32 KB
    __shared__ unsigned int whist[8][NB];            // 4 KB; reused as binof[]
    __shared__ unsigned int base[NB];
    __shared__ unsigned int cur[NB];
    __shared__ unsigned int gbase[NB];
    __shared__ unsigned int ntot_s;
    unsigned char* binof = (unsigned char*)whist;    // alias: dead after phase 2

    int t = threadIdx.x;
    int wave = t >> 6;
    int ebase = blockIdx.x * T_EDGES;

    // uniform weights -> SGPRs
    float wf[12], wsv[12];
#pragma unroll
    for (int i = 0; i < 12; ++i) { wf[i] = uniform_f(Wf + i); wsv[i] = uniform_f(Ws + i); }
    float bf0 = uniform_f(bfv + 0), bf1 = uniform_f(bfv + 1);
    float bs0 = uniform_f(bsv + 0), bs1 = uniform_f(bsv + 1);

    for (int i = t; i < 8 * NB; i += P1_THREADS) ((unsigned int*)whist)[i] = 0;
    LIGHT_BARRIER();

    // phase 1: histogram; keep dst AND src in registers
    int d[EPT], sI[EPT];
#pragma unroll
    for (int i = 0; i < EPT; ++i) {
        int e = ebase + i * P1_THREADS + t;
        if (e < N_EDGES) {
            d[i]  = __builtin_nontemporal_load(ei + N_EDGES + e);
            sI[i] = __builtin_nontemporal_load(ei + e);
        } else { d[i] = -1; sI[i] = 0; }
        if (d[i] >= 0)
            atomicAdd(&whist[wave][((unsigned)d[i]) >> BIN_SHIFT], 1u);
    }
    LIGHT_BARRIER();

    // ---- issue chunk A gathers (i = 0..3): overlap the scan + atomics ----
    float2 xdA[4], xsA[4], eaA[4];
#pragma unroll
    for (int i = 0; i < 4; ++i) {
        int e  = ebase + i * P1_THREADS + t;
        int ec = e < N_EDGES ? e : 0;
        int dd = d[i] >= 0 ? d[i] : 0;
        int ss = d[i] >= 0 ? sI[i] : 0;
        xdA[i] = ((const float2*)x)[dd];
        xsA[i] = ((const float2*)x)[ss];
        eaA[i] = ntload_f2((const float2*)ea + ec);
    }
    __builtin_amdgcn_sched_barrier(0);   // keep issues above the scan

    // phase 2: per-bin totals, exclusive scan (wave 0, 2 bins/lane), reserve.
    // Returning global atomics issued here; gbase written after phase 3.
    unsigned g0 = 0, g1 = 0;
    if (t < 64) {
        unsigned tot0 = 0, tot1 = 0;
#pragma unroll
        for (int w = 0; w < 8; ++w) { tot0 += whist[w][2*t]; tot1 += whist[w][2*t+1]; }
        unsigned pair = tot0 + tot1;
        unsigned v = pair;
#pragma unroll
        for (int off = 1; off < 64; off <<= 1) {
            unsigned u = __shfl_up(v, off);
            if (t >= off) v += u;
        }
        unsigned excl = v - pair;
        base[2*t]   = excl;        cur[2*t]   = excl;
        base[2*t+1] = excl + tot0; cur[2*t+1] = excl + tot0;
        if (t == 63) ntot_s = v;
        g0 = tot0 ? atomicAdd(&cursors[2*t],   tot0) : 0u;
        g1 = tot1 ? atomicAdd(&cursors[2*t+1], tot1) : 0u;
    }
    LIGHT_BARRIER();   // cur/base visible; chunk A loads still in flight

    // ---- issue chunk B gathers (i = 4..7) ----
    float2 xdB[4], xsB[4], eaB[4];
#pragma unroll
    for (int i = 0; i < 4; ++i) {
        int e  = ebase + (i + 4) * P1_THREADS + t;
        int ec = e < N_EDGES ? e : 0;
        int dd = d[i+4] >= 0 ? d[i+4] : 0;
        int ss = d[i+4] >= 0 ? sI[i+4] : 0;
        xdB[i] = ((const float2*)x)[dd];
        xsB[i] = ((const float2*)x)[ss];
        eaB[i] = ntload_f2((const float2*)ea + ec);
    }
    __builtin_amdgcn_sched_barrier(0);   // B issues stay above compute(A)

    // ---- compute chunk A (B's 12 loads in flight), then chunk B ----
#pragma unroll
    for (int half = 0; half < 2; ++half) {
#pragma unroll
        for (int i = 0; i < 4; ++i) {
            int idx = half * 4 + i;
            if (d[idx] < 0) continue;
            int dst = d[idx];
            float2 xd = half ? xdB[i] : xdA[i];
            float2 xs = half ? xsB[i] : xsA[i];
            float2 ev = half ? eaB[i] : eaA[i];
            float z0 = xd.x, z1 = xd.y, z2 = xs.x, z3 = xs.y, z4 = ev.x, z5 = ev.y;

            float f0 = bf0 + z0*wf[0] + z1*wf[2] + z2*wf[4] + z3*wf[6] + z4*wf[8]  + z5*wf[10];
            float f1 = bf1 + z0*wf[1] + z1*wf[3] + z2*wf[5] + z3*wf[7] + z4*wf[9]  + z5*wf[11];
            float s0 = bs0 + z0*wsv[0] + z1*wsv[2] + z2*wsv[4] + z3*wsv[6] + z4*wsv[8]  + z5*wsv[10];
            float s1 = bs1 + z0*wsv[1] + z1*wsv[3] + z2*wsv[5] + z3*wsv[7] + z4*wsv[9]  + z5*wsv[11];

            float m0 = (1.f/(1.f+__expf(-f0))) * (fmaxf(s0,0.f) + __logf(1.f+__expf(-fabsf(s0))));
            float m1 = (1.f/(1.f+__expf(-f1))) * (fmaxf(s1,0.f) + __logf(1.f+__expf(-fabsf(s1))));

            int b = (int)((unsigned)dst >> BIN_SHIFT);
            unsigned slot = atomicAdd(&cur[b], 1u);
            unsigned long long pk = 0ull;     // neutral: adds 0.0 to node b<<12
            if (m0 < M_MAX && m1 < M_MAX) {
                unsigned fx0 = __float2uint_rn(m0 * FXS);
                unsigned fx1 = __float2uint_rn(m1 * FXS);
                pk = (unsigned long long)((unsigned)dst & (BIN_NODES - 1))
                   | ((unsigned long long)fx0 << 12)
                   | ((unsigned long long)fx1 << 37);
            } else {
                unsigned oi = atomicAdd(ovf_cnt, 1u);
                if (oi < OVF_CAP) ovf[oi] = make_float4(__int_as_float(dst), m0, m1, 0.f);
            }
            sorted[slot] = pk;
            binof[slot] = (unsigned char)b;
        }
    }
    if (t < 64) { gbase[2*t] = g0; gbase[2*t+1] = g1; }   // atomics long since returned
    __syncthreads();

    // phase 4: coalesced flush (runs of ~32 edges = 256B contiguous)
    int ntot = (int)ntot_s;
    for (int p = t; p < ntot; p += P1_THREADS) {
        int lo = (int)binof[p];
        unsigned gpos = gbase[lo] + (unsigned)(p - (int)base[lo]);
        unsigned long long v = sorted[p];
        if (gpos < BIN_CAP) {
            __builtin_nontemporal_store(v, &bins[(size_t)lo * BIN_CAP + gpos]);
        } else {                          // cap overflow (p~1e-9): exact replay
            int local = (int)(v & (BIN_NODES - 1));
            float m0 = (float)((unsigned)((v >> 12) & 0x1FFFFFFu)) * FXI;
            float m1 = (float)((unsigned)((v >> 37) & 0x1FFFFFFu)) * FXI;
            int dst = (lo << BIN_SHIFT) + local;
            unsigned oi = atomicAdd(ovf_cnt, 1u);
            if (oi < OVF_CAP) ovf[oi] = make_float4(__int_as_float(dst), m0, m1, 0.f);
        }
    }
}

// ===========================================================================
// Pass 2: K=4 sub-blocks per bin; 32KB private SoA LDS slice (full 32-bank
// spread for the atomics); AoS float2-pair epilogue for the pool.
// ===========================================================================
__global__ __launch_bounds__(512, 8) void p2_kernel(
    const unsigned long long* __restrict__ bins,
    const unsigned int* __restrict__ cursors,
    float* __restrict__ scratch)
{
    __shared__ float acc[SLICE_F];        // 32 KB: [0..4095]=m0, [4096..8191]=m1
    int b = blockIdx.x >> 2;
    int k = blockIdx.x & 3;
    int t = threadIdx.x;
#pragma unroll
    for (int i = t; i < SLICE_F; i += 512) acc[i] = 0.f;
    __syncthreads();

    int n = (int)min(cursors[b], (unsigned)BIN_CAP);
    int s = (n * k) / K, e = (n * (k + 1)) / K;
    const unsigned long long* bp = bins + (size_t)b * BIN_CAP;
    for (int i = s + t; i < e; i += 512) {
        unsigned long long v = __builtin_nontemporal_load(bp + i);
        int local = (int)(v & (BIN_NODES - 1));
        float m0 = (float)((unsigned)((v >> 12) & 0x1FFFFFFu)) * FXI;
        float m1 = (float)((unsigned)((v >> 37) & 0x1FFFFFFu)) * FXI;
        atomicAdd(&acc[local],             m0);
        atomicAdd(&acc[BIN_NODES + local], m1);
    }
    __syncthreads();

    // AoS epilogue: float4 = {m0[2i], m1[2i], m0[2i+1], m1[2i+1]}
    float4* dst = (float4*)(scratch + (size_t)(b * K + k) * SLICE_F);
#pragma unroll
    for (int i = t; i < BIN_NODES / 2; i += 512) {
        float a0 = acc[2*i],             a1 = acc[2*i + 1];
        float b0 = acc[BIN_NODES + 2*i], b1 = acc[BIN_NODES + 2*i + 1];
        dst[i] = make_float4(a0, b0, a1, b1);
    }
}

// Replay overflow edges into slice k=0 (statistically never taken).
__global__ __launch_bounds__(256) void ovf_kernel(
    const float4* __restrict__ ovf, const unsigned int* __restrict__ ovf_cnt,
    float* __restrict__ scratch)
{
    int n = (int)min(*ovf_cnt, (unsigned)OVF_CAP);
    for (int i = threadIdx.x; i < n; i += 256) {
        float4 r = ovf[i];
        int dst = __float_as_int(r.x);
        int b = dst >> BIN_SHIFT, local = dst & (BIN_NODES - 1);
        float* p = scratch + (size_t)(b * K) * SLICE_F + 2 * local;
        unsafeAtomicAdd(p,     r.y);
        unsafeAtomicAdd(p + 1, r.z);
    }
}

// Segment boundaries of sorted batch -> starts[0..N_GRAPHS]; both branches.
__global__ __launch_bounds__(256) void starts_kernel(
    const int* __restrict__ ba, const int* __restrict__ bb,
    unsigned int* __restrict__ sa, unsigned int* __restrict__ sb)
{
    int blk = blockIdx.x;
    const int* batch = ba;
    unsigned int* starts = sa;
    if (blk >= SGRID) { blk -= SGRID; batch = bb; starts = sb; }
    int i = blk * 256 + threadIdx.x;
    if (i >= N_NODES) return;
    int b1 = batch[i];
    if (i == 0) {
        for (int g = 0; g <= b1; ++g) starts[g] = 0;
    } else {
        int b0 = batch[i - 1];
        for (int g = b0 + 1; g <= b1; ++g) starts[g] = i;
    }
    if (i == N_NODES - 1) {
        for (int g = b1 + 1; g <= N_GRAPHS; ++g) starts[g] = N_NODES;
    }
}

// Pool: 4 graphs per block (one wave each); agg = sum of K slices (AoS
// float2), consecutive nodes -> coalesced 8B loads in each slice.
__global__ __launch_bounds__(256) void pool2_kernel(
    const float* __restrict__ x, const float* __restrict__ scratch,
    const unsigned int* __restrict__ starts,
    const float* __restrict__ W1, const float* __restrict__ b1,
    float* __restrict__ mean_out)
{
    int wave = threadIdx.x >> 6, lane = threadIdx.x & 63;
    int g = blockIdx.x * 4 + wave;

    float w00 = W1[0], w01 = W1[1], w02 = W1[2];
    float w10 = W1[3], w11 = W1[4], w12 = W1[5];
    float c0 = b1[0], c1 = b1[1], c2 = b1[2];

    const float2* sc2 = (const float2*)scratch;
    int s = (int)starts[g], e = (int)starts[g + 1];
    float a0 = 0.f, a1 = 0.f, a2 = 0.f;
    for (int i = s + lane; i < e; i += 64) {
        int b = i >> BIN_SHIFT, local = i & (BIN_NODES - 1);
        size_t f2base = (size_t)(b * K) * BIN_NODES + local;   // slice = 4096 f2
        float2 g0 = sc2[f2base];
        float2 g1 = sc2[f2base + BIN_NODES];
        float2 g2 = sc2[f2base + 2 * BIN_NODES];
        float2 g3 = sc2[f2base + 3 * BIN_NODES];
        float2 xv = ((const float2*)x)[i];
        float h0 = xv.x + g0.x + g1.x + g2.x + g3.x;
        float h1 = xv.y + g0.y + g1.y + g2.y + g3.y;
        a0 += fmaxf(h0*w00 + h1*w10 + c0, 0.f);
        a1 += fmaxf(h0*w01 + h1*w11 + c1, 0.f);
        a2 += fmaxf(h0*w02 + h1*w12 + c2, 0.f);
    }
#pragma unroll
    for (int off = 32; off; off >>= 1) {
        a0 += __shfl_down(a0, off);
        a1 += __shfl_down(a1, off);
        a2 += __shfl_down(a2, off);
    }
    if (lane == 0) {
        float inv = 1.0f / fmaxf((float)(e - s), 1.0f);
        mean_out[3*(size_t)g]     = a0 * inv;
        mean_out[3*(size_t)g + 1] = a1 * inv;
        mean_out[3*(size_t)g + 2] = a2 * inv;
    }
}

// Final MLP + MSE loss (single block).
__global__ __launch_bounds__(1024) void final_kernel(
    const float* __restrict__ ma, const float* __restrict__ mb,
    const float* __restrict__ W2, const float* __restrict__ b2,
    const float* __restrict__ targets,
    float* __restrict__ out)
{
    __shared__ float red[1024];
    float w0 = W2[0], w1 = W2[1], w2 = W2[2], w3 = W2[3], w4 = W2[4], w5 = W2[5];
    float bias = b2[0];

    float lsum = 0.f;
    for (int g = threadIdx.x; g < N_GRAPHS; g += 1024) {
        float v = bias
                + ma[3*(size_t)g]*w0 + ma[3*(size_t)g+1]*w1 + ma[3*(size_t)g+2]*w2
                + mb[3*(size_t)g]*w3 + mb[3*(size_t)g+1]*w4 + mb[3*(size_t)g+2]*w5;
        v = fmaxf(v, 0.f);
        out[g] = v;
        float d = v - targets[g];
        lsum += d * d;
    }
    red[threadIdx.x] = lsum;
    __syncthreads();
#pragma unroll
    for (int off = 512; off; off >>= 1) {
        if (threadIdx.x < (unsigned)off) red[threadIdx.x] += red[threadIdx.x + off];
        __syncthreads();
    }
    if (threadIdx.x == 0) out[N_GRAPHS] = red[0] * (1.0f / (float)N_GRAPHS);
}

// ===========================================================================
// Fallback path (ws too small): R2's u64-packed global-atomic kernel.
// ===========================================================================
#define FB_SCALE 4194304.0f
#define FB_INV   2.384185791015625e-07f

__global__ __launch_bounds__(256) void fb_edge_kernel(
    const float* __restrict__ x, const int* __restrict__ ei,
    const float* __restrict__ ea,
    const float* __restrict__ Wf, const float* __restrict__ bfv,
    const float* __restrict__ Ws, const float* __restrict__ bsv,
    unsigned long long* __restrict__ agg)
{
    float wf[12], ws[12];
#pragma unroll
    for (int i = 0; i < 12; ++i) { wf[i] = Wf[i]; ws[i] = Ws[i]; }
    float bf0 = bfv[0], bf1 = bfv[1], bs0 = bsv[0], bs1 = bsv[1];

    int e = blockIdx.x * 256 + threadIdx.x;
    int src = ei[e];
    int dst = ei[N_EDGES + e];
    float2 xd = ((const float2*)x)[dst];
    float2 xs = ((const float2*)x)[src];
    float2 ev = ((const float2*)ea)[e];
    float z0 = xd.x, z1 = xd.y, z2 = xs.x, z3 = xs.y, z4 = ev.x, z5 = ev.y;

    float f0 = bf0 + z0*wf[0] + z1*wf[2] + z2*wf[4] + z3*wf[6] + z4*wf[8]  + z5*wf[10];
    float f1 = bf1 + z0*wf[1] + z1*wf[3] + z2*wf[5] + z3*wf[7] + z4*wf[9]  + z5*wf[11];
    float s0 = bs0 + z0*ws[0] + z1*ws[2] + z2*ws[4] + z3*ws[6] + z4*ws[8]  + z5*ws[10];
    float s1 = bs1 + z0*ws[1] + z1*ws[3] + z2*ws[5] + z3*ws[7] + z4*ws[9]  + z5*ws[11];

    float m0 = (1.f/(1.f+__expf(-f0))) * (fmaxf(s0,0.f) + __logf(1.f+__expf(-fabsf(s0))));
    float m1 = (1.f/(1.f+__expf(-f1))) * (fmaxf(s1,0.f) + __logf(1.f+__expf(-fabsf(s1))));

    unsigned int fx0 = __float2uint_rn(m0 * FB_SCALE);
    unsigned int fx1 = __float2uint_rn(m1 * FB_SCALE);
    atomicAdd(&agg[dst], (unsigned long long)fx0 | ((unsigned long long)fx1 << 32));
}

__global__ __launch_bounds__(64) void fb_pool_kernel(
    const float* __restrict__ x, const unsigned long long* __restrict__ agg,
    const int* __restrict__ batch,
    const float* __restrict__ W1, const float* __restrict__ b1,
    float* __restrict__ mean_out)
{
    int b = blockIdx.x;
    float w00 = W1[0], w01 = W1[1], w02 = W1[2];
    float w10 = W1[3], w11 = W1[4], w12 = W1[5];
    float c0 = b1[0], c1 = b1[1], c2 = b1[2];

    int lo = 0, hi = N_NODES;
    while (lo < hi) { int mid = (lo + hi) >> 1; if (batch[mid] < b) lo = mid + 1; else hi = mid; }
    int seg_s = lo;
    hi = N_NODES;
    while (lo < hi) { int mid = (lo + hi) >> 1; if (batch[mid] < b + 1) lo = mid + 1; else hi = mid; }
    int seg_e = lo;

    float a0 = 0.f, a1 = 0.f, a2 = 0.f;
    for (int i = seg_s + (int)threadIdx.x; i < seg_e; i += 64) {
        unsigned long long v = agg[i];
        float g0 = (float)(unsigned int)(v & 0xffffffffull) * FB_INV;
        float g1 = (float)(unsigned int)(v >> 32) * FB_INV;
        float2 xv = ((const float2*)x)[i];
        float h0 = xv.x + g0, h1 = xv.y + g1;
        a0 += fmaxf(h0*w00 + h1*w10 + c0, 0.f);
        a1 += fmaxf(h0*w01 + h1*w11 + c1, 0.f);
        a2 += fmaxf(h0*w02 + h1*w12 + c2, 0.f);
    }
#pragma unroll
    for (int off = 32; off; off >>= 1) {
        a0 += __shfl_down(a0, off);
        a1 += __shfl_down(a1, off);
        a2 += __shfl_down(a2, off);
    }
    if (threadIdx.x == 0) {
        float inv = 1.0f / fmaxf((float)(seg_e - seg_s), 1.0f);
        mean_out[3*(size_t)b]     = a0 * inv;
        mean_out[3*(size_t)b + 1] = a1 * inv;
        mean_out[3*(size_t)b + 2] = a2 * inv;
    }
}

extern "C" void kernel_launch(void* const* d_in, const int* in_sizes, int n_in,
                              void* d_out, int out_size, void* d_ws, size_t ws_size,
                              hipStream_t stream) {
    const float* x_a     = (const float*)d_in[0];
    const int*   ei_a    = (const int*)  d_in[1];
    const float* ea_a    = (const float*)d_in[2];
    const int*   batch_a = (const int*)  d_in[3];
    const float* x_b     = (const float*)d_in[4];
    const int*   ei_b    = (const int*)  d_in[5];
    const float* ea_b    = (const float*)d_in[6];
    const int*   batch_b = (const int*)  d_in[7];
    const float* targets = (const float*)d_in[8];
    const float* Wf = (const float*)d_in[10];
    const float* bf = (const float*)d_in[11];
    const float* Ws = (const float*)d_in[12];
    const float* bs = (const float*)d_in[13];
    const float* W1 = (const float*)d_in[14];
    const float* b1 = (const float*)d_in[15];
    const float* W2 = (const float*)d_in[16];
    const float* b2 = (const float*)d_in[17];
    float* out = (float*)d_out;
    char* ws = (char*)d_ws;

    if (ws_size >= WS_NEED) {
        unsigned int* curs_a   = (unsigned int*)(ws + OFF_CURS_A);
        unsigned int* curs_b   = (unsigned int*)(ws + OFF_CURS_B);
        unsigned int* ovfc_a   = (unsigned int*)(ws + OFF_OVFC_A);
        unsigned int* ovfc_b   = (unsigned int*)(ws + OFF_OVFC_B);
        unsigned int* starts_a = (unsigned int*)(ws + OFF_STARTS_A);
        unsigned int* starts_b = (unsigned int*)(ws + OFF_STARTS_B);
        float* mean_a = (float*)(ws + OFF_MEAN_A);
        float* mean_b = (float*)(ws + OFF_MEAN_B);
        float4* ovf_a = (float4*)(ws + OFF_OVF_A);
        float4* ovf_b = (float4*)(ws + OFF_OVF_B);
        float* scratch = (float*)(ws + OFF_SCRATCH);            // shared A/B
        unsigned long long* bins = (unsigned long long*)(ws + OFF_BINS);

        hipMemsetAsync(ws, 0, ZERO_SMALL, stream);

        starts_kernel<<<2 * SGRID, 256, 0, stream>>>(batch_a, batch_b, starts_a, starts_b);

        // branch A (pool_a must precede p2_b: scratch is reused)
        p1_kernel<<<P1_GRID, P1_THREADS, 0, stream>>>(x_a, ei_a, ea_a, Wf, bf, Ws, bs,
                                                      bins, curs_a, ovfc_a, ovf_a);
        p2_kernel<<<P2_GRID, 512, 0, stream>>>(bins, curs_a, scratch);
        ovf_kernel<<<1, 256, 0, stream>>>(ovf_a, ovfc_a, scratch);
        pool2_kernel<<<N_GRAPHS / 4, 256, 0, stream>>>(x_a, scratch, starts_a, W1, b1, mean_a);

        // branch B
        p1_kernel<<<P1_GRID, P1_THREADS, 0, stream>>>(x_b, ei_b, ea_b, Wf, bf, Ws, bs,
                                                      bins, curs_b, ovfc_b, ovf_b);
        p2_kernel<<<P2_GRID, 512, 0, stream>>>(bins, curs_b, scratch);
        ovf_kernel<<<1, 256, 0, stream>>>(ovf_b, ovfc_b, scratch);
        pool2_kernel<<<N_GRAPHS / 4, 256, 0, stream>>>(x_b, scratch, starts_b, W1, b1, mean_b);

        final_kernel<<<1, 1024, 0, stream>>>(mean_a, mean_b, W2, b2, targets, out);
    } else {
        // Fallback: R2 path (u64 packed global atomics), needs ~8.1 MB ws.
        unsigned long long* aggu_a = (unsigned long long*)ws;
        unsigned long long* aggu_b = aggu_a + (size_t)N_NODES;
        float* mean_a = (float*)(aggu_b + (size_t)N_NODES);
        float* mean_b = mean_a + 3 * (size_t)N_GRAPHS;

        hipMemsetAsync(ws, 0, 2 * (size_t)N_NODES * sizeof(unsigned long long), stream);
        fb_edge_kernel<<<N_EDGES / 256, 256, 0, stream>>>(x_a, ei_a, ea_a, Wf, bf, Ws, bs, aggu_a);
        fb_edge_kernel<<<N_EDGES / 256, 256, 0, stream>>>(x_b, ei_b, ea_b, Wf, bf, Ws, bs, aggu_b);
        fb_pool_kernel<<<N_GRAPHS, 64, 0, stream>>>(x_a, aggu_a, batch_a, W1, b1, mean_a);
        fb_pool_kernel<<<N_GRAPHS, 64, 0, stream>>>(x_b, aggu_b, batch_b, W1, b1, mean_b);
        final_kernel<<<1, 1024, 0, stream>>>(mean_a, mean_b, W2, b2, targets, out);
    }
}

// Round 4
// 655.874 us; speedup vs baseline: 1.1830x; 1.1257x over previous
//
#include <hip/hip_runtime.h>

#define N_NODES 500000
#define N_EDGES 8000000
#define N_GRAPHS 4096

// ---------------- binned-aggregation v7 ----------------
// v6 -> v7: split the MLP across passes. p1 computes only the src/edge-side
// partials (16 FMA, ONE gather x[src]); the dst-side FMAs, sigmoid/softplus
// and the accumulation move to p2, where dst is bin-local (the bin's 32KB x
// region is L1-resident, so the x[dst] gather is ~free there). Transport:
// 4 partials quantized 13-bit (range +-8, step 2^-9) + 12-bit local = 64b.
// q0==0x1FFF is a skip-sentinel; out-of-range partials go to the exact
// ovf path, replayed by p2's k==0 sub-block (ovf_kernel dispatch removed).
// p1 uses launch_bounds(512,6): measured occupancy never exceeded ~73%
// (3 blocks/CU), so the old (512,8)/64-VGPR cap only caused scratch spills
// (R3: FETCH 103->246MB) -- 85 VGPRs lets the gather batch live in regs.
#define NB 128
#define BIN_SHIFT 12
#define BIN_NODES 4096
#define NBINS 123                   // ceil(500000/4096)
#define BIN_CAP 66560               // mean 65041, sigma ~254 -> +6sigma
#define T_EDGES 4096
#define P1_THREADS 512
#define EPT (T_EDGES / P1_THREADS)  // 8
#define P1_GRID ((N_EDGES + T_EDGES - 1) / T_EDGES)   // 1954
#define K 4                         // sub-blocks per bin in p2
#define P2_GRID (NBINS * K)         // 492
#define SLICE_F (BIN_NODES * 2)     // 8192 floats = 32KB per slice
#define QS 512.0f                   // quant: q = rn(p*512 + 4096), 13 bits
#define QI (1.0f / 512.0f)
#define P_MAX 7.98f                 // |partial| bound; beyond -> exact ovf
#define SENT 0x1FFFu                // q0 sentinel: skip entry
#define OVF_CAP 4096                // records of 2x float4 = 32B
#define SGRID ((N_NODES + 255) / 256)

// ---------------- ws layout (byte offsets) ----------------
#define OFF_CURS_A   0          // 128 u32
#define OFF_CURS_B   512
#define OFF_OVFC_A   1024
#define OFF_OVFC_B   1280
#define ZERO_SMALL   1536       // memset range per call
#define OFF_STARTS_A 4096       // 4097 u32, padded
#define OFF_STARTS_B 20736
#define OFF_MEAN_A   37376      // 4096*3 f32
#define OFF_MEAN_B   86528
#define OFF_OVF_A    135680     // 4096 * 32B records
#define OFF_OVF_B    266752
#define OFF_SCRATCH  397824     // NBINS*K*SLICE_F f32 = 16,121,856 B (shared A/B)
#define OFF_BINS     16519680   // NBINS*BIN_CAP u64 = 65,495,040 B (shared A/B)
#define WS_NEED      82014720ull

__device__ __forceinline__ float2 ntload_f2(const float2* p) {
    unsigned long long v = __builtin_nontemporal_load((const unsigned long long*)p);
    float2 r;
    r.x = __uint_as_float((unsigned int)v);
    r.y = __uint_as_float((unsigned int)(v >> 32));
    return r;
}

__device__ __forceinline__ float uniform_f(const float* p) {
    return __uint_as_float(__builtin_amdgcn_readfirstlane(__float_as_uint(*p)));
}

// ===========================================================================
// Pass 1: src-side partial MLP + LDS counting sort by dst bin.
// ===========================================================================
__global__ __launch_bounds__(512, 6) void p1_kernel(
    const float* __restrict__ x, const int* __restrict__ ei,
    const float* __restrict__ ea,
    const float* __restrict__ Wf, const float* __restrict__ Ws,
    unsigned long long* __restrict__ bins, unsigned int* __restrict__ cursors,
    unsigned int* __restrict__ ovf_cnt, float4* __restrict__ ovf)
{
    __shared__ unsigned long long sorted[T_EDGES];   // 32 KB
    __shared__ unsigned int whist[8][NB];            // 4 KB; reused as binof[]
    __shared__ unsigned int base[NB];
    __shared__ unsigned int cur[NB];
    __shared__ unsigned int gbase[NB];
    __shared__ unsigned int ntot_s;
    unsigned char* binof = (unsigned char*)whist;    // alias: dead after phase 2

    int t = threadIdx.x;
    int wave = t >> 6;
    int ebase = blockIdx.x * T_EDGES;

    // src/edge-side weights -> SGPR: wf[i]=Wf[4+i], ws[i]=Ws[4+i]
    float wf[8], ws[8];
#pragma unroll
    for (int i = 0; i < 8; ++i) { wf[i] = uniform_f(Wf + 4 + i); ws[i] = uniform_f(Ws + 4 + i); }

    for (int i = t; i < 8 * NB; i += P1_THREADS) ((unsigned int*)whist)[i] = 0;
    __syncthreads();

    // phase 1: histogram; keep dst AND src in registers
    int d[EPT], sI[EPT];
#pragma unroll
    for (int i = 0; i < EPT; ++i) {
        int e = ebase + i * P1_THREADS + t;
        if (e < N_EDGES) {
            d[i]  = __builtin_nontemporal_load(ei + N_EDGES + e);
            sI[i] = __builtin_nontemporal_load(ei + e);
        } else { d[i] = -1; sI[i] = 0; }
        if (d[i] >= 0)
            atomicAdd(&whist[wave][((unsigned)d[i]) >> BIN_SHIFT], 1u);
    }
    __syncthreads();

    // phase 2: per-bin totals, exclusive scan (wave 0, 2 bins/lane), reserve.
    // Returning global atomics issued here; gbase written after phase 3.
    unsigned g0 = 0, g1 = 0;
    if (t < 64) {
        unsigned tot0 = 0, tot1 = 0;
#pragma unroll
        for (int w = 0; w < 8; ++w) { tot0 += whist[w][2*t]; tot1 += whist[w][2*t+1]; }
        unsigned pair = tot0 + tot1;
        unsigned v = pair;
#pragma unroll
        for (int off = 1; off < 64; off <<= 1) {
            unsigned u = __shfl_up(v, off);
            if (t >= off) v += u;
        }
        unsigned excl = v - pair;
        base[2*t]   = excl;        cur[2*t]   = excl;
        base[2*t+1] = excl + tot0; cur[2*t+1] = excl + tot0;
        if (t == 63) ntot_s = v;
        g0 = tot0 ? atomicAdd(&cursors[2*t],   tot0) : 0u;
        g1 = tot1 ? atomicAdd(&cursors[2*t+1], tot1) : 0u;
    }
    __syncthreads();

    // phase 3a: batch the gathers (x[src] is the only gather left; ea coalesced)
    float2 xs[EPT], ev[EPT];
#pragma unroll
    for (int i = 0; i < EPT; ++i) {
        int e = ebase + i * P1_THREADS + t;
        if (e < N_EDGES) {
            xs[i] = ((const float2*)x)[sI[i]];
            ev[i] = ntload_f2((const float2*)ea + e);
        }
    }

    // phase 3b: 16 FMA partials, quantize, place into sorted LDS slots
#pragma unroll
    for (int i = 0; i < EPT; ++i) {
        if (d[i] < 0) continue;
        int dst = d[i];
        float z2 = xs[i].x, z3 = xs[i].y, z4 = ev[i].x, z5 = ev[i].y;
        float p0 = z2*wf[0] + z3*wf[2] + z4*wf[4] + z5*wf[6];
        float p1 = z2*wf[1] + z3*wf[3] + z4*wf[5] + z5*wf[7];
        float p2 = z2*ws[0] + z3*ws[2] + z4*ws[4] + z5*ws[6];
        float p3 = z2*ws[1] + z3*ws[3] + z4*ws[5] + z5*ws[7];

        int b = (int)((unsigned)dst >> BIN_SHIFT);
        unsigned local = (unsigned)dst & (BIN_NODES - 1);
        unsigned slot = atomicAdd(&cur[b], 1u);
        float mx = fmaxf(fmaxf(fabsf(p0), fabsf(p1)), fmaxf(fabsf(p2), fabsf(p3)));
        unsigned long long pk;
        if (mx < P_MAX) {
            unsigned q0 = __float2uint_rn(p0 * QS + 4096.0f);
            unsigned q1 = __float2uint_rn(p1 * QS + 4096.0f);
            unsigned q2 = __float2uint_rn(p2 * QS + 4096.0f);
            unsigned q3 = __float2uint_rn(p3 * QS + 4096.0f);
            pk = (unsigned long long)local
               | ((unsigned long long)q0 << 12)
               | ((unsigned long long)q1 << 25)
               | ((unsigned long long)q2 << 38)
               | ((unsigned long long)q3 << 51);
        } else {
            pk = (unsigned long long)local | ((unsigned long long)SENT << 12);
            unsigned oi = atomicAdd(ovf_cnt, 1u);
            if (oi < OVF_CAP) {
                ovf[2*oi]   = make_float4(__int_as_float(dst), p0, p1, p2);
                ovf[2*oi+1] = make_float4(p3, 0.f, 0.f, 0.f);
            }
        }
        sorted[slot] = pk;
        binof[slot] = (unsigned char)b;
    }
    if (t < 64) { gbase[2*t] = g0; gbase[2*t+1] = g1; }
    __syncthreads();

    // phase 4: coalesced flush (runs of ~32 edges = 256B contiguous)
    int ntot = (int)ntot_s;
    for (int p = t; p < ntot; p += P1_THREADS) {
        int lo = (int)binof[p];
        unsigned gpos = gbase[lo] + (unsigned)(p - (int)base[lo]);
        unsigned long long v = sorted[p];
        if (gpos < BIN_CAP) {
            __builtin_nontemporal_store(v, &bins[(size_t)lo * BIN_CAP + gpos]);
        } else {                          // cap overflow (p~1e-9): exact replay
            unsigned q0 = (unsigned)(v >> 12) & 0x1FFFu;
            if (q0 != SENT) {
                int local = (int)(v & (BIN_NODES - 1));
                int dst = (lo << BIN_SHIFT) + local;
                float p0 = (float)q0 * QI - 8.f;
                float p1 = (float)((unsigned)(v >> 25) & 0x1FFFu) * QI - 8.f;
                float p2 = (float)((unsigned)(v >> 38) & 0x1FFFu) * QI - 8.f;
                float p3 = (float)((unsigned)(v >> 51) & 0x1FFFu) * QI - 8.f;
                unsigned oi = atomicAdd(ovf_cnt, 1u);
                if (oi < OVF_CAP) {
                    ovf[2*oi]   = make_float4(__int_as_float(dst), p0, p1, p2);
                    ovf[2*oi+1] = make_float4(p3, 0.f, 0.f, 0.f);
                }
            }
        }
    }
}

// ===========================================================================
// Pass 2: dst-side MLP + nonlinearity + accumulate. K=4 sub-blocks per bin;
// 32KB private SoA LDS slice; x[dst] gather hits the bin's 32KB L1-resident
// region. k==0 sub-block also replays the (statistically empty) ovf list.
// ===========================================================================
__global__ __launch_bounds__(512, 8) void p2_kernel(
    const unsigned long long* __restrict__ bins,
    const unsigned int* __restrict__ cursors,
    const float* __restrict__ x,
    const float* __restrict__ Wf, const float* __restrict__ bfv,
    const float* __restrict__ Ws, const float* __restrict__ bsv,
    const float4* __restrict__ ovf, const unsigned int* __restrict__ ovf_cnt,
    float* __restrict__ scratch)
{
    __shared__ float acc[SLICE_F];        // [0..4095]=m0, [4096..8191]=m1
    int b = blockIdx.x >> 2;
    int k = blockIdx.x & 3;
    int t = threadIdx.x;

    float wf0 = uniform_f(Wf+0), wf1 = uniform_f(Wf+1), wf2 = uniform_f(Wf+2), wf3 = uniform_f(Wf+3);
    float ws0 = uniform_f(Ws+0), ws1 = uniform_f(Ws+1), ws2 = uniform_f(Ws+2), ws3 = uniform_f(Ws+3);
    float bf0 = uniform_f(bfv+0), bf1 = uniform_f(bfv+1);
    float bs0 = uniform_f(bsv+0), bs1 = uniform_f(bsv+1);
    float bf0m = bf0 - 8.f, bf1m = bf1 - 8.f, bs0m = bs0 - 8.f, bs1m = bs1 - 8.f;

#pragma unroll
    for (int i = t; i < SLICE_F; i += 512) acc[i] = 0.f;
    __syncthreads();

    const float2* xb = (const float2*)x + ((size_t)b << BIN_SHIFT);
    int n = (int)min(cursors[b], (unsigned)BIN_CAP);
    int s = (n * k) / K, e = (n * (k + 1)) / K;
    const unsigned long long* bp = bins + (size_t)b * BIN_CAP;
    for (int i = s + t; i < e; i += 512) {
        unsigned long long v = __builtin_nontemporal_load(bp + i);
        unsigned q0 = (unsigned)(v >> 12) & 0x1FFFu;
        int local = (int)(v & (BIN_NODES - 1));
        float2 xd = xb[local];
        if (q0 != SENT) {
            float f0 = bf0m + (float)q0 * QI                            + xd.x*wf0 + xd.y*wf2;
            float f1 = bf1m + (float)((unsigned)(v >> 25) & 0x1FFFu)*QI + xd.x*wf1 + xd.y*wf3;
            float s0 = bs0m + (float)((unsigned)(v >> 38) & 0x1FFFu)*QI + xd.x*ws0 + xd.y*ws2;
            float s1 = bs1m + (float)((unsigned)(v >> 51) & 0x1FFFu)*QI + xd.x*ws1 + xd.y*ws3;
            float m0 = (1.f/(1.f+__expf(-f0))) * (fmaxf(s0,0.f) + __logf(1.f+__expf(-fabsf(s0))));
            float m1 = (1.f/(1.f+__expf(-f1))) * (fmaxf(s1,0.f) + __logf(1.f+__expf(-fabsf(s1))));
            atomicAdd(&acc[local],             m0);
            atomicAdd(&acc[BIN_NODES + local], m1);
        }
    }

    if (k == 0) {   // ovf replay for this bin (n_ovf ~ 0)
        int no = (int)min(*ovf_cnt, (unsigned)OVF_CAP);
        for (int i = t; i < no; i += 512) {
            float4 r0 = ovf[2*i];
            float4 r1 = ovf[2*i+1];
            int dst = __float_as_int(r0.x);
            if ((dst >> BIN_SHIFT) == b) {
                int local = dst & (BIN_NODES - 1);
                float2 xd = xb[local];
                float f0 = bf0 + r0.y + xd.x*wf0 + xd.y*wf2;
                float f1 = bf1 + r0.z + xd.x*wf1 + xd.y*wf3;
                float s0 = bs0 + r0.w + xd.x*ws0 + xd.y*ws2;
                float s1 = bs1 + r1.x + xd.x*ws1 + xd.y*ws3;
                float m0 = (1.f/(1.f+__expf(-f0))) * (fmaxf(s0,0.f) + __logf(1.f+__expf(-fabsf(s0))));
                float m1 = (1.f/(1.f+__expf(-f1))) * (fmaxf(s1,0.f) + __logf(1.f+__expf(-fabsf(s1))));
                atomicAdd(&acc[local],             m0);
                atomicAdd(&acc[BIN_NODES + local], m1);
            }
        }
    }
    __syncthreads();

    // AoS epilogue: float4 = {m0[2i], m1[2i], m0[2i+1], m1[2i+1]}
    float4* dst = (float4*)(scratch + (size_t)(b * K + k) * SLICE_F);
#pragma unroll
    for (int i = t; i < BIN_NODES / 2; i += 512) {
        dst[i] = make_float4(acc[2*i], acc[BIN_NODES + 2*i],
                             acc[2*i + 1], acc[BIN_NODES + 2*i + 1]);
    }
}

// Segment boundaries of sorted batch -> starts[0..N_GRAPHS]; both branches.
__global__ __launch_bounds__(256) void starts_kernel(
    const int* __restrict__ ba, const int* __restrict__ bb,
    unsigned int* __restrict__ sa, unsigned int* __restrict__ sb)
{
    int blk = blockIdx.x;
    const int* batch = ba;
    unsigned int* starts = sa;
    if (blk >= SGRID) { blk -= SGRID; batch = bb; starts = sb; }
    int i = blk * 256 + threadIdx.x;
    if (i >= N_NODES) return;
    int b1 = batch[i];
    if (i == 0) {
        for (int g = 0; g <= b1; ++g) starts[g] = 0;
    } else {
        int b0 = batch[i - 1];
        for (int g = b0 + 1; g <= b1; ++g) starts[g] = i;
    }
    if (i == N_NODES - 1) {
        for (int g = b1 + 1; g <= N_GRAPHS; ++g) starts[g] = N_NODES;
    }
}

// Pool: 4 graphs per block (one wave each); agg = sum of K slices (AoS
// float2), consecutive nodes -> coalesced 8B loads in each slice.
__global__ __launch_bounds__(256) void pool2_kernel(
    const float* __restrict__ x, const float* __restrict__ scratch,
    const unsigned int* __restrict__ starts,
    const float* __restrict__ W1, const float* __restrict__ b1,
    float* __restrict__ mean_out)
{
    int wave = threadIdx.x >> 6, lane = threadIdx.x & 63;
    int g = blockIdx.x * 4 + wave;

    float w00 = W1[0], w01 = W1[1], w02 = W1[2];
    float w10 = W1[3], w11 = W1[4], w12 = W1[5];
    float c0 = b1[0], c1 = b1[1], c2 = b1[2];

    const float2* sc2 = (const float2*)scratch;
    int s = (int)starts[g], e = (int)starts[g + 1];
    float a0 = 0.f, a1 = 0.f, a2 = 0.f;
    for (int i = s + lane; i < e; i += 64) {
        int b = i >> BIN_SHIFT, local = i & (BIN_NODES - 1);
        size_t f2base = (size_t)(b * K) * BIN_NODES + local;   // slice = 4096 f2
        float2 g0 = sc2[f2base];
        float2 g1 = sc2[f2base + BIN_NODES];
        float2 g2 = sc2[f2base + 2 * BIN_NODES];
        float2 g3 = sc2[f2base + 3 * BIN_NODES];
        float2 xv = ((const float2*)x)[i];
        float h0 = xv.x + g0.x + g1.x + g2.x + g3.x;
        float h1 = xv.y + g0.y + g1.y + g2.y + g3.y;
        a0 += fmaxf(h0*w00 + h1*w10 + c0, 0.f);
        a1 += fmaxf(h0*w01 + h1*w11 + c1, 0.f);
        a2 += fmaxf(h0*w02 + h1*w12 + c2, 0.f);
    }
#pragma unroll
    for (int off = 32; off; off >>= 1) {
        a0 += __shfl_down(a0, off);
        a1 += __shfl_down(a1, off);
        a2 += __shfl_down(a2, off);
    }
    if (lane == 0) {
        float inv = 1.0f / fmaxf((float)(e - s), 1.0f);
        mean_out[3*(size_t)g]     = a0 * inv;
        mean_out[3*(size_t)g + 1] = a1 * inv;
        mean_out[3*(size_t)g + 2] = a2 * inv;
    }
}

// Final MLP + MSE loss (single block).
__global__ __launch_bounds__(1024) void final_kernel(
    const float* __restrict__ ma, const float* __restrict__ mb,
    const float* __restrict__ W2, const float* __restrict__ b2,
    const float* __restrict__ targets,
    float* __restrict__ out)
{
    __shared__ float red[1024];
    float w0 = W2[0], w1 = W2[1], w2 = W2[2], w3 = W2[3], w4 = W2[4], w5 = W2[5];
    float bias = b2[0];

    float lsum = 0.f;
    for (int g = threadIdx.x; g < N_GRAPHS; g += 1024) {
        float v = bias
                + ma[3*(size_t)g]*w0 + ma[3*(size_t)g+1]*w1 + ma[3*(size_t)g+2]*w2
                + mb[3*(size_t)g]*w3 + mb[3*(size_t)g+1]*w4 + mb[3*(size_t)g+2]*w5;
        v = fmaxf(v, 0.f);
        out[g] = v;
        float d = v - targets[g];
        lsum += d * d;
    }
    red[threadIdx.x] = lsum;
    __syncthreads();
#pragma unroll
    for (int off = 512; off; off >>= 1) {
        if (threadIdx.x < (unsigned)off) red[threadIdx.x] += red[threadIdx.x + off];
        __syncthreads();
    }
    if (threadIdx.x == 0) out[N_GRAPHS] = red[0] * (1.0f / (float)N_GRAPHS);
}

// ===========================================================================
// Fallback path (ws too small): u64-packed global-atomic kernel.
// ===========================================================================
#define FB_SCALE 4194304.0f
#define FB_INV   2.384185791015625e-07f

__global__ __launch_bounds__(256) void fb_edge_kernel(
    const float* __restrict__ x, const int* __restrict__ ei,
    const float* __restrict__ ea,
    const float* __restrict__ Wf, const float* __restrict__ bfv,
    const float* __restrict__ Ws, const float* __restrict__ bsv,
    unsigned long long* __restrict__ agg)
{
    float wf[12], ws[12];
#pragma unroll
    for (int i = 0; i < 12; ++i) { wf[i] = Wf[i]; ws[i] = Ws[i]; }
    float bf0 = bfv[0], bf1 = bfv[1], bs0 = bsv[0], bs1 = bsv[1];

    int e = blockIdx.x * 256 + threadIdx.x;
    int src = ei[e];
    int dst = ei[N_EDGES + e];
    float2 xd = ((const float2*)x)[dst];
    float2 xs = ((const float2*)x)[src];
    float2 ev = ((const float2*)ea)[e];
    float z0 = xd.x, z1 = xd.y, z2 = xs.x, z3 = xs.y, z4 = ev.x, z5 = ev.y;

    float f0 = bf0 + z0*wf[0] + z1*wf[2] + z2*wf[4] + z3*wf[6] + z4*wf[8]  + z5*wf[10];
    float f1 = bf1 + z0*wf[1] + z1*wf[3] + z2*wf[5] + z3*wf[7] + z4*wf[9]  + z5*wf[11];
    float s0 = bs0 + z0*ws[0] + z1*ws[2] + z2*ws[4] + z3*ws[6] + z4*ws[8]  + z5*ws[10];
    float s1 = bs1 + z0*ws[1] + z1*ws[3] + z2*ws[5] + z3*ws[7] + z4*ws[9]  + z5*ws[11];

    float m0 = (1.f/(1.f+__expf(-f0))) * (fmaxf(s0,0.f) + __logf(1.f+__expf(-fabsf(s0))));
    float m1 = (1.f/(1.f+__expf(-f1))) * (fmaxf(s1,0.f) + __logf(1.f+__expf(-fabsf(s1))));

    unsigned int fx0 = __float2uint_rn(m0 * FB_SCALE);
    unsigned int fx1 = __float2uint_rn(m1 * FB_SCALE);
    atomicAdd(&agg[dst], (unsigned long long)fx0 | ((unsigned long long)fx1 << 32));
}

__global__ __launch_bounds__(64) void fb_pool_kernel(
    const float* __restrict__ x, const unsigned long long* __restrict__ agg,
    const int* __restrict__ batch,
    const float* __restrict__ W1, const float* __restrict__ b1,
    float* __restrict__ mean_out)
{
    int b = blockIdx.x;
    float w00 = W1[0], w01 = W1[1], w02 = W1[2];
    float w10 = W1[3], w11 = W1[4], w12 = W1[5];
    float c0 = b1[0], c1 = b1[1], c2 = b1[2];

    int lo = 0, hi = N_NODES;
    while (lo < hi) { int mid = (lo + hi) >> 1; if (batch[mid] < b) lo = mid + 1; else hi = mid; }
    int seg_s = lo;
    hi = N_NODES;
    while (lo < hi) { int mid = (lo + hi) >> 1; if (batch[mid] < b + 1) lo = mid + 1; else hi = mid; }
    int seg_e = lo;

    float a0 = 0.f, a1 = 0.f, a2 = 0.f;
    for (int i = seg_s + (int)threadIdx.x; i < seg_e; i += 64) {
        unsigned long long v = agg[i];
        float g0 = (float)(unsigned int)(v & 0xffffffffull) * FB_INV;
        float g1 = (float)(unsigned int)(v >> 32) * FB_INV;
        float2 xv = ((const float2*)x)[i];
        float h0 = xv.x + g0, h1 = xv.y + g1;
        a0 += fmaxf(h0*w00 + h1*w10 + c0, 0.f);
        a1 += fmaxf(h0*w01 + h1*w11 + c1, 0.f);
        a2 += fmaxf(h0*w02 + h1*w12 + c2, 0.f);
    }
#pragma unroll
    for (int off = 32; off; off >>= 1) {
        a0 += __shfl_down(a0, off);
        a1 += __shfl_down(a1, off);
        a2 += __shfl_down(a2, off);
    }
    if (threadIdx.x == 0) {
        float inv = 1.0f / fmaxf((float)(seg_e - seg_s), 1.0f);
        mean_out[3*(size_t)b]     = a0 * inv;
        mean_out[3*(size_t)b + 1] = a1 * inv;
        mean_out[3*(size_t)b + 2] = a2 * inv;
    }
}

extern "C" void kernel_launch(void* const* d_in, const int* in_sizes, int n_in,
                              void* d_out, int out_size, void* d_ws, size_t ws_size,
                              hipStream_t stream) {
    const float* x_a     = (const float*)d_in[0];
    const int*   ei_a    = (const int*)  d_in[1];
    const float* ea_a    = (const float*)d_in[2];
    const int*   batch_a = (const int*)  d_in[3];
    const float* x_b     = (const float*)d_in[4];
    const int*   ei_b    = (const int*)  d_in[5];
    const float* ea_b    = (const float*)d_in[6];
    const int*   batch_b = (const int*)  d_in[7];
    const float* targets = (const float*)d_in[8];
    const float* Wf = (const float*)d_in[10];
    const float* bf = (const float*)d_in[11];
    const float* Ws = (const float*)d_in[12];
    const float* bs = (const float*)d_in[13];
    const float* W1 = (const float*)d_in[14];
    const float* b1 = (const float*)d_in[15];
    const float* W2 = (const float*)d_in[16];
    const float* b2 = (const float*)d_in[17];
    float* out = (float*)d_out;
    char* ws = (char*)d_ws;

    if (ws_size >= WS_NEED) {
        unsigned int* curs_a   = (unsigned int*)(ws + OFF_CURS_A);
        unsigned int* curs_b   = (unsigned int*)(ws + OFF_CURS_B);
        unsigned int* ovfc_a   = (unsigned int*)(ws + OFF_OVFC_A);
        unsigned int* ovfc_b   = (unsigned int*)(ws + OFF_OVFC_B);
        unsigned int* starts_a = (unsigned int*)(ws + OFF_STARTS_A);
        unsigned int* starts_b = (unsigned int*)(ws + OFF_STARTS_B);
        float* mean_a = (float*)(ws + OFF_MEAN_A);
        float* mean_b = (float*)(ws + OFF_MEAN_B);
        float4* ovf_a = (float4*)(ws + OFF_OVF_A);
        float4* ovf_b = (float4*)(ws + OFF_OVF_B);
        float* scratch = (float*)(ws + OFF_SCRATCH);            // shared A/B
        unsigned long long* bins = (unsigned long long*)(ws + OFF_BINS);

        hipMemsetAsync(ws, 0, ZERO_SMALL, stream);

        starts_kernel<<<2 * SGRID, 256, 0, stream>>>(batch_a, batch_b, starts_a, starts_b);

        // branch A (pool_a must precede p2_b: scratch is reused)
        p1_kernel<<<P1_GRID, P1_THREADS, 0, stream>>>(x_a, ei_a, ea_a, Wf, Ws,
                                                      bins, curs_a, ovfc_a, ovf_a);
        p2_kernel<<<P2_GRID, 512, 0, stream>>>(bins, curs_a, x_a, Wf, bf, Ws, bs,
                                               ovf_a, ovfc_a, scratch);
        pool2_kernel<<<N_GRAPHS / 4, 256, 0, stream>>>(x_a, scratch, starts_a, W1, b1, mean_a);

        // branch B
        p1_kernel<<<P1_GRID, P1_THREADS, 0, stream>>>(x_b, ei_b, ea_b, Wf, Ws,
                                                      bins, curs_b, ovfc_b, ovf_b);
        p2_kernel<<<P2_GRID, 512, 0, stream>>>(bins, curs_b, x_b, Wf, bf, Ws, bs,
                                               ovf_b, ovfc_b, scratch);
        pool2_kernel<<<N_GRAPHS / 4, 256, 0, stream>>>(x_b, scratch, starts_b, W1, b1, mean_b);

        final_kernel<<<1, 1024, 0, stream>>>(mean_a, mean_b, W2, b2, targets, out);
    } else {
        // Fallback: u64 packed global atomics, needs ~8.1 MB ws.
        unsigned long long* aggu_a = (unsigned long long*)ws;
        unsigned long long* aggu_b = aggu_a + (size_t)N_NODES;
        float* mean_a = (float*)(aggu_b + (size_t)N_NODES);
        float* mean_b = mean_a + 3 * (size_t)N_GRAPHS;

        hipMemsetAsync(ws, 0, 2 * (size_t)N_NODES * sizeof(unsigned long long), stream);
        fb_edge_kernel<<<N_EDGES / 256, 256, 0, stream>>>(x_a, ei_a, ea_a, Wf, bf, Ws, bs, aggu_a);
        fb_edge_kernel<<<N_EDGES / 256, 256, 0, stream>>>(x_b, ei_b, ea_b, Wf, bf, Ws, bs, aggu_b);
        fb_pool_kernel<<<N_GRAPHS, 64, 0, stream>>>(x_a, aggu_a, batch_a, W1, b1, mean_a);
        fb_pool_kernel<<<N_GRAPHS, 64, 0, stream>>>(x_b, aggu_b, batch_b, W1, b1, mean_b);
        final_kernel<<<1, 1024, 0, stream>>>(mean_a, mean_b, W2, b2, targets, out);
    }
}